// Round 3
// baseline (544.979 us; speedup 1.0000x reference)
//
#include <hip/hip_runtime.h>
#include <stdint.h>

// GRU encoder B=512,T=512,H=256,IN=2 — R11: head/tail micro-squeeze.
// R10 base: phase-split MFMAs ({R,N} -> r,tanh chain -> {Z}), reg-resident
// gate constants, zero-shuffle gate layout, W pinned in VGPRs.
// R11 changes:
//  1. Explicit A-frag array a[8]: the 8 ds_read_b128 issue back-to-back at
//     step top (right after barrier) and are read ONCE (no phase-B re-read;
//     latency front-loaded under gate-input FMAs + x prefetch).
//  2. #pragma unroll 2 on the step loop: (s&1) ping-pong parity becomes
//     compile-time, killing per-iter buffer address VALU and letting the
//     scheduler prep next-iter addresses across the barrier.
//  3. Branch-free x prefetch index ((s+1)&511).
// MFMA count/shape unchanged: 96 MFMA-instr/SIMD/step ~= 1862 cyc pipe floor
// (77% of current step); this round attacks the ~570 cyc serial remainder.

typedef _Float16 v8h  __attribute__((ext_vector_type(8)));
typedef float    f32x4 __attribute__((ext_vector_type(4)));

#define BB 512
#define TT 512
#define HH 256
#define NT 48    // 768/16 col tiles
#define KT 8     // 256/32 k tiles
#define HSTR 288 // padded h16 stride (halves): batch0/1 -> disjoint banks

// Wp4[(ct*KT + kt)*64 + lane] = 8 halves W_hh[16ct + (lane&15)][32kt + (lane>>4)*8 + j]
__global__ void prep_pack(const float* __restrict__ Whh, uint4* __restrict__ Wp4) {
    int n = blockIdx.x * blockDim.x + threadIdx.x;   // [0, 24576)
    int lane = n & 63;
    int kt = (n >> 6) & (KT - 1);
    int ct = n >> 9;
    int row = 16 * ct + (lane & 15);
    int k0  = 32 * kt + (lane >> 4) * 8;
    const float* src = Whh + (size_t)row * HH + k0;
    v8h v;
    #pragma unroll
    for (int j = 0; j < 8; ++j) v[j] = (_Float16)src[j];
    Wp4[n] = __builtin_bit_cast(uint4, v);
}

__device__ __forceinline__ float sigmoid_f(float x) {
    return __builtin_amdgcn_rcpf(1.f + __expf(-x));
}
__device__ __forceinline__ float tanh_f(float x) {
    x = fminf(fmaxf(x, -15.f), 15.f);
    float e = __expf(-2.f * x);
    return (1.f - e) * __builtin_amdgcn_rcpf(1.f + e);
}

__global__ void __launch_bounds__(512, 1)
gru_persist(const float* __restrict__ x,        // [B,T,2]
            const int* __restrict__ len,        // [B]
            const float* __restrict__ h0,       // [B,H]
            const float* __restrict__ Wih,      // [768,2]
            const float* __restrict__ bih,      // [768]
            const float* __restrict__ bhh,      // [768]
            const uint4* __restrict__ Wp4,      // MFMA-fragment-packed fp16 W_hh
            float* __restrict__ out)            // [B,H]
{
    __shared__ __align__(16) _Float16 h16[2][2][HSTR];  // [buf][batch][e]

    const int tid  = threadIdx.x;
    const int lane = tid & 63;
    const int w    = tid >> 6;          // wave 0..7
    const int b0   = blockIdx.x * 2;

    // ---- W B-fragments for this wave's 6 tiles: 192 dwords in regs ----
    v8h wfr[6][KT];
    {
        const int cts[6] = {2*w, 2*w+1, 16+2*w, 16+2*w+1, 32+2*w, 32+2*w+1};
        #pragma unroll
        for (int c = 0; c < 6; ++c)
            #pragma unroll
            for (int kt = 0; kt < KT; ++kt)
                wfr[c][kt] = __builtin_bit_cast(v8h, Wp4[(cts[c] * KT + kt) * 64 + lane]);
    }
    #pragma unroll
    for (int c = 0; c < 6; ++c)
        #pragma unroll
        for (int kt = 0; kt < KT; ++kt)
            asm volatile("" : "+v"(wfr[c][kt]));   // reg-resident, not remat

    // ---- gate-slot mapping: one slot per lane ----
    // batch = (lane>>4)&1 ; e = 32w + (lane&15) + 16*(lane>>5)
    const int batch = (lane >> 4) & 1;
    const int e = 32 * w + (lane & 15) + ((lane >> 5) << 4);

    // ---- loop-invariant gate constants in registers ----
    const float ccx = bih[e] + bhh[e];                     // r bias
    const float ccy = bih[HH + e] + bhh[HH + e];           // z bias
    const float ccz = bih[2 * HH + e];                     // n input bias
    const float ccw = bhh[2 * HH + e];                     // n hidden bias
    const float wxr0 = Wih[2 * e],            wxr1 = Wih[2 * e + 1];
    const float wxz0 = Wih[2 * (HH + e)],     wxz1 = Wih[2 * (HH + e) + 1];
    const float wxn0 = Wih[2 * (2 * HH + e)], wxn1 = Wih[2 * (2 * HH + e) + 1];

    float hp = h0[(size_t)(b0 + batch) * HH + e];
    h16[0][batch][e] = (_Float16)hp;     // every (batch,e) covered exactly once

    const int l0 = len[b0], l1 = len[b0 + 1];
    const int lm  = l0 > l1 ? l0 : l1;   // uniform loop bound
    const int lmy = batch ? l1 : l0;     // per-lane length
    const float2* xp = (const float2*)x + (size_t)(b0 + batch) * TT;
    float* op = out + (size_t)(b0 + batch) * HH + e;

    // A-frag: row m = lane&15 -> batch (m>>2)&1, k chunk = (lane>>4)*8.
    // 8 distinct 16B addrs/wave (2 batch x 4 kchunk), conflict-free.
    const _Float16* abase = &h16[0][(lane >> 2) & 1][(lane >> 4) * 8];

    __syncthreads();

    float2 xv = xp[0];
    #pragma unroll 2
    for (int s = 0; s < lm; ++s) {
        const _Float16* ap = abase + (s & 1) * (2 * HSTR);  // static per unroll copy

        // ---- A-frags: 8x ds_read_b128 issued back-to-back, read once ----
        v8h a[KT];
        #pragma unroll
        for (int kt = 0; kt < KT; ++kt)
            a[kt] = *(const v8h*)(ap + kt * 32);

        // work that hides the LDS latency:
        const float2 xvn = xp[(s + 1) & (TT - 1)];   // prefetch next step's x
        const float gR = fmaf(xv.x, wxr0, fmaf(xv.y, wxr1, ccx));
        const float gZ = fmaf(xv.x, wxz0, fmaf(xv.y, wxz1, ccy));
        const float gN = fmaf(xv.x, wxn0, fmaf(xv.y, wxn1, ccz));

        f32x4 d0 = {0.f,0.f,0.f,0.f}, d1 = {0.f,0.f,0.f,0.f};
        f32x4 d2 = {0.f,0.f,0.f,0.f}, d3 = {0.f,0.f,0.f,0.f};
        f32x4 d4 = {0.f,0.f,0.f,0.f}, d5 = {0.f,0.f,0.f,0.f};

        // ---- phase A: R tiles (d0,d1) + N tiles (d4,d5) ----
        #pragma unroll
        for (int kt = 0; kt < KT; ++kt) {
            d0 = __builtin_amdgcn_mfma_f32_16x16x32_f16(a[kt], wfr[0][kt], d0, 0, 0, 0);
            d1 = __builtin_amdgcn_mfma_f32_16x16x32_f16(a[kt], wfr[1][kt], d1, 0, 0, 0);
            d4 = __builtin_amdgcn_mfma_f32_16x16x32_f16(a[kt], wfr[4][kt], d4, 0, 0, 0);
            d5 = __builtin_amdgcn_mfma_f32_16x16x32_f16(a[kt], wfr[5][kt], d5, 0, 0, 0);
        }

        // long dependent chain: r -> n (two chained transcendentals),
        // hidden under phase-B MFMA issue.
        const bool hi = lane >= 32;
        const float uR = hi ? d1[0] : d0[0];
        const float uN = hi ? d5[0] : d4[0];
        const float r = sigmoid_f(uR + gR);
        const float n = tanh_f(gN + r * (uN + ccw));

        // ---- phase B: Z tiles (d2,d3) — independent of r/n chain ----
        #pragma unroll
        for (int kt = 0; kt < KT; ++kt) {
            d2 = __builtin_amdgcn_mfma_f32_16x16x32_f16(a[kt], wfr[2][kt], d2, 0, 0, 0);
            d3 = __builtin_amdgcn_mfma_f32_16x16x32_f16(a[kt], wfr[3][kt], d3, 0, 0, 0);
        }

        const float uZ = hi ? d3[0] : d2[0];
        const float z = sigmoid_f(uZ + gZ);
        float hn = fmaf(z, hp - n, n);
        hn = (s < lmy) ? hn : hp;            // freeze finished batch
        h16[(s & 1) ^ 1][batch][e] = (_Float16)hn;
        hp = hn;
        if (s == lmy - 1) *op = hn;
        xv = xvn;
        __syncthreads();   // new h16 buffer visible for next step's A reads
    }
}

extern "C" void kernel_launch(void* const* d_in, const int* in_sizes, int n_in,
                              void* d_out, int out_size, void* d_ws, size_t ws_size,
                              hipStream_t stream) {
    const float* x    = (const float*)d_in[0];
    const int*   lenp = (const int*)d_in[1];
    const float* h0   = (const float*)d_in[2];
    const float* Wih  = (const float*)d_in[3];
    const float* Whh  = (const float*)d_in[4];
    const float* bih  = (const float*)d_in[5];
    const float* bhh  = (const float*)d_in[6];
    float* out = (float*)d_out;

    uint4* Wp4 = (uint4*)d_ws;   // 384 KB scratch

    prep_pack<<<NT * KT * 64 / 256, 256, 0, stream>>>(Whh, Wp4);
    gru_persist<<<BB / 2, 512, 0, stream>>>(x, lenp, h0, Wih, bih, bhh, Wp4, out);
}

// Round 4
// 349.341 us; speedup vs baseline: 1.5600x; 1.5600x over previous
//
#include <hip/hip_runtime.h>
#include <stdint.h>

// GRU encoder B=512,T=512,H=256,IN=2 — R12: i8 MFMA (K=64), halved MFMA floor.
// R11 lesson: explicit a[8]+unroll2 scheduling regressed — compiler's inline
// ds_read/MFMA interleave is better; reverted to R10 structure.
// R12 change: h quantized to i8 (scale 127; h in (-1,1) strictly since h is a
// convex combo of tanh outputs from h0=0), W_hh quantized to i8 (scale 2032;
// |W|<1/16 by construction -> |W_q|<=127, exact bound). mfma_i32_16x16x64_i8:
// 48 col-tiles x 4 k-tiles = 192 MFMA/block/step = 48/SIMD -> ~980 cyc floor
// (was 96/SIMD f16 ~1862). i32 accum exact; gates/elementwise stay f32; hp
// stays an UNQUANTIZED f32 register (quant error enters only via W*h_q).
// Packing is k-permutation-consistent on both operands (dot invariant), C/D
// layout dtype-independent -> gate extraction identical to f16 version.
// HSTR8=320: batch1 base ≡ 64 mod 128 -> the 8 distinct 16B A-read lines hit
// 8 distinct bank quads -> conflict-free ds_read_b128.

typedef int   v4i   __attribute__((ext_vector_type(4)));
typedef float f32x4 __attribute__((ext_vector_type(4)));

#define BB 512
#define TT 512
#define HH 256
#define NCT 48     // 768/16 col tiles
#define KTI 4      // 256/64 k tiles (i8)
#define HSTR8 320  // padded h8 byte stride per batch
#define WSCALE 2032.0f
#define INVS (1.0f/(2032.0f*127.0f))

// Wp[(ct*KTI + kt)*64 + lane] = 16 bytes W_hh[16ct + (lane&15)][64kt + (lane>>4)*16 + j]
__global__ void prep_pack_i8(const float* __restrict__ Whh, uint4* __restrict__ Wp) {
    int n = blockIdx.x * blockDim.x + threadIdx.x;   // [0, 48*4*64 = 12288)
    int lane = n & 63;
    int kt = (n >> 6) & (KTI - 1);
    int ct = n >> 8;
    int row = 16 * ct + (lane & 15);
    int k0  = 64 * kt + (lane >> 4) * 16;
    const float* src = Whh + (size_t)row * HH + k0;
    uint dw[4];
    #pragma unroll
    for (int d = 0; d < 4; ++d) {
        uint acc = 0;
        #pragma unroll
        for (int j = 0; j < 4; ++j) {
            int q = (int)rintf(src[4 * d + j] * WSCALE);
            q = q < -127 ? -127 : (q > 127 ? 127 : q);
            acc |= ((uint)(q & 0xff)) << (8 * j);
        }
        dw[d] = acc;
    }
    Wp[n] = uint4{dw[0], dw[1], dw[2], dw[3]};
}

__device__ __forceinline__ float sigmoid_f(float x) {
    return __builtin_amdgcn_rcpf(1.f + __expf(-x));
}
__device__ __forceinline__ float tanh_f(float x) {
    x = fminf(fmaxf(x, -15.f), 15.f);
    float e = __expf(-2.f * x);
    return (1.f - e) * __builtin_amdgcn_rcpf(1.f + e);
}

__global__ void __launch_bounds__(512, 1)
gru_persist(const float* __restrict__ x,        // [B,T,2]
            const int* __restrict__ len,        // [B]
            const float* __restrict__ h0,       // [B,H]
            const float* __restrict__ Wih,      // [768,2]
            const float* __restrict__ bih,      // [768]
            const float* __restrict__ bhh,      // [768]
            const uint4* __restrict__ Wp,       // i8-packed W_hh fragments
            float* __restrict__ out)            // [B,H]
{
    __shared__ __align__(16) int8_t h8[2][2][HSTR8];   // [buf][batch][e]

    const int tid  = threadIdx.x;
    const int lane = tid & 63;
    const int w    = tid >> 6;          // wave 0..7
    const int b0   = blockIdx.x * 2;

    // ---- W B-fragments for this wave's 6 tiles: 96 dwords in regs ----
    v4i wfr[6][KTI];
    {
        const int cts[6] = {2*w, 2*w+1, 16+2*w, 16+2*w+1, 32+2*w, 32+2*w+1};
        #pragma unroll
        for (int c = 0; c < 6; ++c)
            #pragma unroll
            for (int kt = 0; kt < KTI; ++kt)
                wfr[c][kt] = __builtin_bit_cast(v4i, Wp[(cts[c] * KTI + kt) * 64 + lane]);
    }
    #pragma unroll
    for (int c = 0; c < 6; ++c)
        #pragma unroll
        for (int kt = 0; kt < KTI; ++kt)
            asm volatile("" : "+v"(wfr[c][kt]));   // reg-resident, not remat

    // ---- gate-slot mapping: one slot per lane ----
    const int batch = (lane >> 4) & 1;
    const int e = 32 * w + (lane & 15) + ((lane >> 5) << 4);

    // ---- loop-invariant gate constants in registers ----
    const float ccx = bih[e] + bhh[e];                     // r bias
    const float ccy = bih[HH + e] + bhh[HH + e];           // z bias
    const float ccz = bih[2 * HH + e];                     // n input bias
    const float ccw = bhh[2 * HH + e];                     // n hidden bias
    const float wxr0 = Wih[2 * e],            wxr1 = Wih[2 * e + 1];
    const float wxz0 = Wih[2 * (HH + e)],     wxz1 = Wih[2 * (HH + e) + 1];
    const float wxn0 = Wih[2 * (2 * HH + e)], wxn1 = Wih[2 * (2 * HH + e) + 1];

    float hp = h0[(size_t)(b0 + batch) * HH + e];
    h8[0][batch][e] = (int8_t)(int)rintf(hp * 127.f);

    const int l0 = len[b0], l1 = len[b0 + 1];
    const int lm  = l0 > l1 ? l0 : l1;   // uniform loop bound
    const int lmy = batch ? l1 : l0;     // per-lane length
    const float2* xp = (const float2*)x + (size_t)(b0 + batch) * TT;
    float* op = out + (size_t)(b0 + batch) * HH + e;

    // A-frag: row m = lane&15 -> batch (m>>2)&1, 16-byte k chunk (lane>>4).
    const int8_t* abase = &h8[0][(lane >> 2) & 1][(lane >> 4) * 16];

    __syncthreads();

    float2 xv = xp[0];
    #pragma unroll 1
    for (int s = 0; s < lm; ++s) {
        const float2 xvn = xp[(s + 1) & (TT - 1)];   // prefetch next step's x

        // input-projection terms (independent of MFMA chain)
        const float gR = fmaf(xv.x, wxr0, fmaf(xv.y, wxr1, ccx));
        const float gZ = fmaf(xv.x, wxz0, fmaf(xv.y, wxz1, ccy));
        const float gN = fmaf(xv.x, wxn0, fmaf(xv.y, wxn1, ccz));

        const int8_t* ap = abase + (s & 1) * (2 * HSTR8);  // h8 ping-pong
        v4i d0 = {0,0,0,0}, d1 = {0,0,0,0};
        v4i d4 = {0,0,0,0}, d5 = {0,0,0,0};
        v4i d2e = {0,0,0,0}, d2o = {0,0,0,0}, d3e = {0,0,0,0}, d3o = {0,0,0,0};

        // ---- phase A: R tiles (d0,d1) + N tiles (d4,d5), 16 MFMA ----
        #pragma unroll
        for (int kt = 0; kt < KTI; ++kt) {
            const v4i a = *(const v4i*)(ap + kt * 64);   // ds_read_b128 broadcast
            d0 = __builtin_amdgcn_mfma_i32_16x16x64_i8(a, wfr[0][kt], d0, 0, 0, 0);
            d1 = __builtin_amdgcn_mfma_i32_16x16x64_i8(a, wfr[1][kt], d1, 0, 0, 0);
            d4 = __builtin_amdgcn_mfma_i32_16x16x64_i8(a, wfr[4][kt], d4, 0, 0, 0);
            d5 = __builtin_amdgcn_mfma_i32_16x16x64_i8(a, wfr[5][kt], d5, 0, 0, 0);
        }

        // long dependent chain: r -> n, hidden under phase-B MFMA issue
        const bool hi = lane >= 32;
        const float uR = (float)(hi ? d1[0] : d0[0]) * INVS;
        const float uN = (float)(hi ? d5[0] : d4[0]) * INVS;
        const float r = sigmoid_f(uR + gR);
        const float n = tanh_f(gN + r * (uN + ccw));

        // ---- phase B: Z tiles, 8 MFMA in 4 chains (dep-gap 4) ----
        #pragma unroll
        for (int kt = 0; kt < KTI; kt += 2) {
            const v4i a0 = *(const v4i*)(ap + kt * 64);
            const v4i a1 = *(const v4i*)(ap + (kt + 1) * 64);
            d2e = __builtin_amdgcn_mfma_i32_16x16x64_i8(a0, wfr[2][kt],     d2e, 0, 0, 0);
            d3e = __builtin_amdgcn_mfma_i32_16x16x64_i8(a0, wfr[3][kt],     d3e, 0, 0, 0);
            d2o = __builtin_amdgcn_mfma_i32_16x16x64_i8(a1, wfr[2][kt + 1], d2o, 0, 0, 0);
            d3o = __builtin_amdgcn_mfma_i32_16x16x64_i8(a1, wfr[3][kt + 1], d3o, 0, 0, 0);
        }

        const int uZi = hi ? (d3e[0] + d3o[0]) : (d2e[0] + d2o[0]);
        const float uZ = (float)uZi * INVS;
        const float z = sigmoid_f(uZ + gZ);
        float hn = fmaf(z, hp - n, n);
        hn = (s < lmy) ? hn : hp;            // freeze finished batch
        h8[(s & 1) ^ 1][batch][e] = (int8_t)(int)rintf(hn * 127.f);
        hp = hn;
        if (s == lmy - 1) *op = hn;
        xv = xvn;
        __syncthreads();   // new h8 buffer visible for next step's A reads
    }
}

extern "C" void kernel_launch(void* const* d_in, const int* in_sizes, int n_in,
                              void* d_out, int out_size, void* d_ws, size_t ws_size,
                              hipStream_t stream) {
    const float* x    = (const float*)d_in[0];
    const int*   lenp = (const int*)d_in[1];
    const float* h0   = (const float*)d_in[2];
    const float* Wih  = (const float*)d_in[3];
    const float* Whh  = (const float*)d_in[4];
    const float* bih  = (const float*)d_in[5];
    const float* bhh  = (const float*)d_in[6];
    float* out = (float*)d_out;

    uint4* Wp = (uint4*)d_ws;   // 192 KB scratch

    prep_pack_i8<<<NCT * KTI * 64 / 256, 256, 0, stream>>>(Whh, Wp);
    gru_persist<<<BB / 2, 512, 0, stream>>>(x, lenp, h0, Wih, bih, bhh, Wp, out);
}